// Round 1
// 430.815 us; speedup vs baseline: 1.0324x; 1.0324x over previous
//
#include <hip/hip_runtime.h>

// EvoBinarizedLayer: out[p,b,o] = x@W0 + (1-x)@W1  =  x@(W0-W1) + colsum_i(W1)
// x:[32,512,1024] {0,1} fp32; w:[2,32,1024,1024] {0,1} fp32; out fp32.
// Memory-bound (384 MB min traffic, ~61us floor @6.3TB/s). bf16 MFMA, exact.
//
// R1: XCD-aware work swizzle. 256 blocks = 8 XCDs x 32. work=(bid%8)*32+bid/8
// gives each XCD a contiguous chunk of 32 work items; chunks are p-major so
// each XCD owns 4 complete p-slices -> zero inter-XCD data sharing. Within a
// chunk, the 2 b-blocks sharing a w-panel and the 4 o-blocks sharing an
// x-panel are co-resident on one XCD's L2 (per-iter footprint ~1.25MB < 4MB).
// Cuts HBM fetch from ~786MB (w read 2x, x read 4x across XCDs) toward 320MB.

namespace {

constexpr int PP = 32;
constexpr int BB = 512;
constexpr int II = 1024;
constexpr int OO = 1024;

constexpr int BM = 256;   // b tile
constexpr int BN = 256;   // o tile
constexpr int BK = 32;    // k tile (= one 16x16x32 MFMA K)

constexpr int KPA = 40;   // A LDS row stride in bf16 elems (80B, 16B-aligned)

// B LDS addressing (bf16 elems): [o][k] with 16B pad every 4 rows.
// Keeps ds_read_b128 16B-aligned; spreads transpose-write banks ~8-way.
__device__ __forceinline__ int boff(int o, int k) {
    return o * 40 + (o >> 2) * 8 + k;
}

typedef __attribute__((ext_vector_type(8))) short bf16x8;
typedef __attribute__((ext_vector_type(4))) float f32x4;

constexpr int A_BYTES = BM * KPA * 2;                 // 20480
constexpr int B_BYTES = (BN * 40 + (BN / 4) * 8) * 2; // 21504
constexpr int SMEM_BYTES = A_BYTES + B_BYTES;         // 41984 < 64KB

// fp32 -> bf16 by truncation: exact for {0,+-1}. Pack two into one u32 (lo=first).
__device__ __forceinline__ unsigned pk2(float lo, float hi) {
    return (__float_as_uint(lo) >> 16) | (__float_as_uint(hi) & 0xFFFF0000u);
}

__global__ __launch_bounds__(1024) void ebl_kernel(const float* __restrict__ x,
                                                   const float* __restrict__ w,
                                                   float* __restrict__ out) {
    __shared__ __align__(16) char smem[SMEM_BYTES];
    unsigned short* As = (unsigned short*)smem;            // [BM][KPA] bf16, [b][k]
    unsigned short* Bs = (unsigned short*)(smem + A_BYTES);// boff-layout bf16, [o][k]
    float* Scr    = (float*)smem;            // reused after k-loop: 16 waves x 256 o
    float* ColSum = (float*)(smem + 16384);  // 256 floats (still inside A region)

    const int t  = (int)threadIdx.x;
    const int l  = t & 63;
    const int wv = t >> 6;       // wave 0..15
    const int wm = wv & 3;       // wave m (b) tile
    const int wn = wv >> 2;      // wave n (o) tile
    const int lq = l >> 4;       // quad
    const int ln = l & 15;

    // XCD-aware swizzle: XCD k (= bid%8, round-robin dispatch) gets the
    // contiguous work chunk [32k, 32k+32). work decode is p-major:
    //   work = y + 2*o_blk + 8*p_local-ish  ->  p = work>>3 spans 4 values/chunk.
    const int bid = (int)blockIdx.x;
    const int wid = (bid & 7) * 32 + (bid >> 3);
    const int p   = wid >> 3;               // 0..31, 4 per XCD chunk
    const int o0  = ((wid >> 1) & 3) * BN;  // o-block
    const int b0  = (wid & 1) * BM;         // b-block

    const float* xp  = x + ((size_t)p * BB + b0) * II;
    const float* w0p = w + (size_t)p * II * OO;
    const float* w1p = w + (size_t)(PP + p) * II * OO;

    // A staging: 2 loads/thread: rows a_row, a_row+128; 8 lanes cover a 32-float row seg.
    const int a_row = t >> 3;
    const int a_col = (t & 7) * 4;
    // B staging: wave wv loads w rows 2wv, 2wv+1; 64 lanes cover a full 1KB row.
    const int b_colg = 4 * l;

    // Fragment LDS read offsets are k-loop invariant.
    int a_rd[4], b_rd[4];
#pragma unroll
    for (int mt = 0; mt < 4; ++mt)
        a_rd[mt] = (wm * 64 + mt * 16 + ln) * KPA + lq * 8;
#pragma unroll
    for (int nt = 0; nt < 4; ++nt)
        b_rd[nt] = boff(wn * 64 + nt * 16 + ln, lq * 8);

    f32x4 acc[4][4];
#pragma unroll
    for (int mt = 0; mt < 4; ++mt)
#pragma unroll
        for (int nt = 0; nt < 4; ++nt)
            acc[mt][nt] = (f32x4){0.f, 0.f, 0.f, 0.f};

    f32x4 csum = (f32x4){0.f, 0.f, 0.f, 0.f};  // per-lane colsum(W1) partial, o=4l..4l+3

    const float* xa0  = xp + (size_t)a_row * II + a_col;
    const float* xa1  = xp + (size_t)(a_row + 128) * II + a_col;
    const float* wb00 = w0p + (size_t)(2 * wv) * OO + o0 + b_colg;
    const float* wb01 = w0p + (size_t)(2 * wv + 1) * OO + o0 + b_colg;
    const float* wb10 = w1p + (size_t)(2 * wv) * OO + o0 + b_colg;
    const float* wb11 = w1p + (size_t)(2 * wv + 1) * OO + o0 + b_colg;

    for (int kk = 0; kk < II; kk += BK) {
        // ---- global loads (fp32, dwordx4, fully coalesced) ----
        f32x4 a0  = *(const f32x4*)(xa0 + kk);
        f32x4 a1  = *(const f32x4*)(xa1 + kk);
        f32x4 p00 = *(const f32x4*)(wb00 + (size_t)kk * OO);
        f32x4 p01 = *(const f32x4*)(wb01 + (size_t)kk * OO);
        f32x4 p10 = *(const f32x4*)(wb10 + (size_t)kk * OO);
        f32x4 p11 = *(const f32x4*)(wb11 + (size_t)kk * OO);

        __syncthreads();  // prior iteration's LDS reads complete

        // ---- A: truncate-convert to bf16, k-contiguous b64 writes ----
        *(uint2*)(&As[a_row * KPA + a_col]) =
            make_uint2(pk2(a0.x, a0.y), pk2(a0.z, a0.w));
        *(uint2*)(&As[(a_row + 128) * KPA + a_col]) =
            make_uint2(pk2(a1.x, a1.y), pk2(a1.z, a1.w));

        // ---- B: diff = W0-W1 (in {-1,0,1}), colsum(W1), register transpose ----
        f32x4 d0 = p00 - p10;   // k = 2wv
        f32x4 d1 = p01 - p11;   // k = 2wv+1
        csum += p10;
        csum += p11;
        const int kloc = 2 * wv;
#pragma unroll
        for (int c = 0; c < 4; ++c)
            *(unsigned*)(&Bs[boff(b_colg + c, kloc)]) = pk2(d0[c], d1[c]);

        __syncthreads();

        // ---- MFMA: wave tile 64x64, one K=32 step ----
        bf16x8 af[4], bfm[4];
#pragma unroll
        for (int mt = 0; mt < 4; ++mt)
            af[mt] = *(const bf16x8*)(&As[a_rd[mt]]);
#pragma unroll
        for (int nt = 0; nt < 4; ++nt)
            bfm[nt] = *(const bf16x8*)(&Bs[b_rd[nt]]);
#pragma unroll
        for (int mt = 0; mt < 4; ++mt)
#pragma unroll
            for (int nt = 0; nt < 4; ++nt)
                acc[mt][nt] = __builtin_amdgcn_mfma_f32_16x16x32_bf16(
                    af[mt], bfm[nt], acc[mt][nt], 0, 0, 0);
    }

    // ---- colsum(W1) reduction: 16 per-wave partials -> 256 column sums ----
    __syncthreads();                       // last MFMA reads done; reuse A region
    *(f32x4*)(&Scr[wv * 256 + l * 4]) = csum;
    __syncthreads();
    if (t < 256) {
        float s = 0.f;
#pragma unroll
        for (int ww = 0; ww < 16; ++ww) s += Scr[ww * 256 + t];
        ColSum[t] = s;
    }
    __syncthreads();

    // ---- epilogue: C/D layout col=lane&15, row=quad*4+reg (m89/m91-verified) ----
    float* op = out + (size_t)p * BB * OO + o0;
#pragma unroll
    for (int nt = 0; nt < 4; ++nt) {
        const int ocol = wn * 64 + nt * 16 + ln;
        const float cs = ColSum[ocol];
#pragma unroll
        for (int mt = 0; mt < 4; ++mt) {
            const int row = b0 + wm * 64 + mt * 16 + lq * 4;
#pragma unroll
            for (int r = 0; r < 4; ++r)
                op[(size_t)(row + r) * OO + ocol] = acc[mt][nt][r] + cs;
        }
    }
}

}  // namespace

extern "C" void kernel_launch(void* const* d_in, const int* in_sizes, int n_in,
                              void* d_out, int out_size, void* d_ws, size_t ws_size,
                              hipStream_t stream) {
    const float* x = (const float*)d_in[0];
    const float* w = (const float*)d_in[1];
    float* out = (float*)d_out;
    dim3 grid(PP * (BB / BM) * (OO / BN), 1, 1);  // 256 blocks, 1/CU
    ebl_kernel<<<grid, dim3(1024, 1, 1), 0, stream>>>(x, w, out);
}